// Round 1
// baseline (1405.996 us; speedup 1.0000x reference)
//
#include <hip/hip_runtime.h>

#define B_ROWS 65536

typedef __attribute__((ext_vector_type(8))) __bf16 bf16x8;
typedef __attribute__((ext_vector_type(4))) float f32x4;
typedef __attribute__((ext_vector_type(8))) unsigned short u16x8;

__device__ __forceinline__ unsigned short f2bf(float f) {
  unsigned int u = __float_as_uint(f);
  u += 0x7fffu + ((u >> 16) & 1u);   // RNE
  return (unsigned short)(u >> 16);
}

__device__ __forceinline__ float elu_f(float v) {
  return v > 0.f ? v : __expf(v) - 1.f;
}

__device__ __forceinline__ void async_ld16(const void* g, void* l) {
  __builtin_amdgcn_global_load_lds(
      (const __attribute__((address_space(1))) void*)g,
      (__attribute__((address_space(3))) void*)l, 16, 0, 0);
}

// ---------------- gating MLP, fp32 (w precision protects the absmax gate) ----
__global__ __launch_bounds__(256) void gating_kernel(
    const float* __restrict__ z, const int* __restrict__ idx,
    const float* __restrict__ Wg1, const float* __restrict__ bg1,
    const float* __restrict__ Wg2, const float* __restrict__ bg2,
    const float* __restrict__ Wg3, const float* __restrict__ bg3,
    float* __restrict__ wq, float* __restrict__ gscr) {
  const size_t row = (size_t)blockIdx.x * 256 + threadIdx.x;
  const float* zr = z + row * 512;
  float* g1 = gscr + row * 128;
  float* g2 = gscr + (size_t)B_ROWS * 128 + row * 128;

  for (int ct = 0; ct < 4; ct++) {            // layer 1 (gathered input)
    float acc[32];
#pragma unroll
    for (int c = 0; c < 32; c++) acc[c] = bg1[ct * 32 + c];
    for (int k = 0; k < 128; k++) {
      float xv = zr[idx[k]];
      const float* wr = Wg1 + k * 128 + ct * 32;
#pragma unroll
      for (int c = 0; c < 32; c++) acc[c] += xv * wr[c];
    }
#pragma unroll
    for (int c = 0; c < 32; c++) g1[ct * 32 + c] = elu_f(acc[c]);
  }
  for (int ct = 0; ct < 4; ct++) {            // layer 2
    float acc[32];
#pragma unroll
    for (int c = 0; c < 32; c++) acc[c] = bg2[ct * 32 + c];
    for (int k = 0; k < 128; k++) {
      float xv = g1[k];
      const float* wr = Wg2 + k * 128 + ct * 32;
#pragma unroll
      for (int c = 0; c < 32; c++) acc[c] += xv * wr[c];
    }
#pragma unroll
    for (int c = 0; c < 32; c++) g2[ct * 32 + c] = elu_f(acc[c]);
  }
  float a3[8];                                // layer 3: raw logits
#pragma unroll
  for (int e = 0; e < 8; e++) a3[e] = bg3[e];
  for (int k = 0; k < 128; k++) {
    float xv = g2[k];
    const float* wr = Wg3 + k * 8;
#pragma unroll
    for (int e = 0; e < 8; e++) a3[e] += xv * wr[e];
  }
#pragma unroll
  for (int e = 0; e < 8; e++) wq[row * 8 + e] = a3[e];
}

// ---------------- z -> bf16 -----------------------------------------------
__global__ __launch_bounds__(256) void convert_bf16_k(
    const float* __restrict__ in, unsigned short* __restrict__ out) {
  size_t i = ((size_t)blockIdx.x * 256 + threadIdx.x) * 8;
  float4 a = *(const float4*)(in + i);
  float4 b = *(const float4*)(in + i + 4);
  u16x8 r;
  r[0] = f2bf(a.x); r[1] = f2bf(a.y); r[2] = f2bf(a.z); r[3] = f2bf(a.w);
  r[4] = f2bf(b.x); r[5] = f2bf(b.y); r[6] = f2bf(b.z); r[7] = f2bf(b.w);
  *(u16x8*)(out + i) = r;
}

// ---------------- W[e][i][o] f32 -> Wt[e][o][i] bf16 (B^T layout) ----------
__global__ __launch_bounds__(256) void transpose_w(
    const float* __restrict__ W1, const float* __restrict__ W2,
    const float* __restrict__ W3, unsigned short* __restrict__ Wt) {
  __shared__ float t[32][33];
  const int le = blockIdx.z;  // layer*8 + e, 0..23
  const float* W = (le < 8) ? W1 : (le < 16) ? W2 : W3;
  const size_t eoff = (size_t)(le & 7) * 262144;
  unsigned short* O = Wt + (size_t)le * 262144;
  const int i0 = blockIdx.y * 32, o0 = blockIdx.x * 32;
  const int tx = threadIdx.x & 31, ty = threadIdx.x >> 5;
#pragma unroll
  for (int s = 0; s < 4; s++)
    t[ty + s * 8][tx] = W[eoff + (size_t)(i0 + ty + s * 8) * 512 + o0 + tx];
  __syncthreads();
#pragma unroll
  for (int s = 0; s < 4; s++)
    O[(size_t)(o0 + ty + s * 8) * 512 + i0 + tx] = f2bf(t[tx][ty + s * 8]);
}

// ---------------- soft-MoE expert layer: out = sum_e w_e*(X@W_e + b_e) -----
// 128x128 tile, BK=64, 4 waves (each 64x64 = 4x4 frags of 16x16x32 bf16 MFMA).
// Staging via global_load_lds(16B) with XOR chunk swizzle; per-expert AGPR
// partial combined into fp32 C with per-row gate weight from LDS.
template <bool ELU, bool OUTBF>
__global__ __launch_bounds__(256, 2) void expert_layer(
    const unsigned short* __restrict__ X,   // 65536 x 512 bf16
    const unsigned short* __restrict__ Wt,  // 8 x 512 x 512 bf16 [e][o][i]
    const float* __restrict__ bias,         // 8 x 512 f32 [e][o]
    const float* __restrict__ wq,           // 65536 x 8 f32
    void* __restrict__ Out) {
  __shared__ short a_tile[128 * 64];   // 16 KB, rows of 8 swizzled 16B chunks
  __shared__ short b_tile[128 * 64];   // 16 KB
  __shared__ float w_lds[8 * 128];     // [e][row]  (transposed for b128 reads)
  __shared__ float bias_lds[8 * 128];  // [e][col]

  const int tid = threadIdx.x;
  const int lane = tid & 63;
  const int wave = tid >> 6;
  const int wr = wave >> 1, wc = wave & 1;
  const int lhi = lane >> 4, llo = lane & 15;

  // XCD-aware swizzle: each XCD owns a contiguous m-range, n fast within it
  const int g = blockIdx.x;
  const int xcd = g & 7;
  const int s = g >> 3;
  const int nb = s & 3;
  const int mb = xcd * 64 + (s >> 2);
  const size_t row0 = (size_t)mb * 128;
  const int col0 = nb * 128;

  for (int i = tid; i < 1024; i += 256) {
    const int e = i >> 7, r = i & 127;
    w_lds[i] = wq[(row0 + r) * 8 + e];
    bias_lds[i] = bias[e * 512 + col0 + r];
  }

  const int srow = tid >> 3;                     // 0..31 staged rows/round
  const int cgo = ((tid & 7) ^ (srow & 7)) << 4; // swizzled global 16B chunk
  const char* Ab = (const char*)X + (row0 + srow) * 1024 + cgo;
  const char* Bb = (const char*)Wt + (size_t)(col0 + srow) * 1024 + cgo;
  char* aL = (char*)a_tile + tid * 16;
  char* bL = (char*)b_tile + tid * 16;

  const f32x4 vzero = {0.f, 0.f, 0.f, 0.f};
  f32x4 C[4][4];
#pragma unroll
  for (int i = 0; i < 4; i++)
#pragma unroll
    for (int j = 0; j < 4; j++) C[i][j] = vzero;

  const int rsw = llo & 7;  // frag-read swizzle key (row & 7)

  for (int e = 0; e < 8; e++) {
    f32x4 acc[4][4];
#pragma unroll
    for (int i = 0; i < 4; i++)
#pragma unroll
      for (int j = 0; j < 4; j++) acc[i][j] = vzero;
    const char* Be = Bb + (size_t)e * 524288;
    for (int kt = 0; kt < 8; kt++) {
      const char* ga = Ab + kt * 128;
      const char* gb = Be + kt * 128;
#pragma unroll
      for (int j = 0; j < 4; j++) {
        async_ld16(ga + j * 32768, aL + j * 4096);
        async_ld16(gb + j * 32768, bL + j * 4096);
      }
      __syncthreads();  // drains vmcnt before barrier
#pragma unroll
      for (int ks = 0; ks < 2; ks++) {
        const int slot = (ks * 4 + lhi) ^ rsw;
        bf16x8 av[4], bv[4];
#pragma unroll
        for (int fm = 0; fm < 4; fm++)
          av[fm] = *(const bf16x8*)((const char*)a_tile +
                                    (wr * 64 + fm * 16 + llo) * 128 + slot * 16);
#pragma unroll
        for (int fn = 0; fn < 4; fn++)
          bv[fn] = *(const bf16x8*)((const char*)b_tile +
                                    (wc * 64 + fn * 16 + llo) * 128 + slot * 16);
#pragma unroll
        for (int fm = 0; fm < 4; fm++)
#pragma unroll
          for (int fn = 0; fn < 4; fn++)
            acc[fm][fn] = __builtin_amdgcn_mfma_f32_16x16x32_bf16(
                av[fm], bv[fn], acc[fm][fn], 0, 0, 0);
      }
      __syncthreads();
    }
    // fp32 combine: C += w[row,e] * P_e   (rows = lhi*4 + r -> one b128 read)
#pragma unroll
    for (int fm = 0; fm < 4; fm++) {
      const f32x4 wv =
          *(const f32x4*)(w_lds + e * 128 + wr * 64 + fm * 16 + lhi * 4);
#pragma unroll
      for (int fn = 0; fn < 4; fn++)
#pragma unroll
        for (int r = 0; r < 4; r++) C[fm][fn][r] += wv[r] * acc[fm][fn][r];
    }
  }

  // bias: C += sum_e w[row,e] * b[e,col]  (once per block)
#pragma unroll
  for (int e = 0; e < 8; e++) {
    f32x4 wv[4];
#pragma unroll
    for (int fm = 0; fm < 4; fm++)
      wv[fm] = *(const f32x4*)(w_lds + e * 128 + wr * 64 + fm * 16 + lhi * 4);
#pragma unroll
    for (int fn = 0; fn < 4; fn++) {
      const float bb = bias_lds[e * 128 + wc * 64 + fn * 16 + llo];
#pragma unroll
      for (int fm = 0; fm < 4; fm++)
#pragma unroll
        for (int r = 0; r < 4; r++) C[fm][fn][r] += wv[fm][r] * bb;
    }
  }

  // epilogue: ELU + store (bf16 h or f32 final)
#pragma unroll
  for (int fm = 0; fm < 4; fm++)
#pragma unroll
    for (int fn = 0; fn < 4; fn++)
#pragma unroll
      for (int r = 0; r < 4; r++) {
        float v = C[fm][fn][r];
        if (ELU) v = elu_f(v);
        const size_t orow = row0 + wr * 64 + fm * 16 + lhi * 4 + r;
        const int ocol = col0 + wc * 64 + fn * 16 + llo;
        if (OUTBF)
          ((unsigned short*)Out)[orow * 512 + ocol] = f2bf(v);
        else
          ((float*)Out)[orow * 512 + ocol] = v;
      }
}

extern "C" void kernel_launch(void* const* d_in, const int* in_sizes, int n_in,
                              void* d_out, int out_size, void* d_ws,
                              size_t ws_size, hipStream_t stream) {
  (void)in_sizes; (void)n_in; (void)out_size; (void)ws_size;
  const float* z   = (const float*)d_in[0];
  const int*   idx = (const int*)d_in[1];
  const float* Wg1 = (const float*)d_in[2];
  const float* bg1 = (const float*)d_in[3];
  const float* Wg2 = (const float*)d_in[4];
  const float* bg2 = (const float*)d_in[5];
  const float* Wg3 = (const float*)d_in[6];
  const float* bg3 = (const float*)d_in[7];
  const float* W1  = (const float*)d_in[8];
  const float* b1  = (const float*)d_in[9];
  const float* W2  = (const float*)d_in[10];
  const float* b2  = (const float*)d_in[11];
  const float* W3  = (const float*)d_in[12];
  const float* b3  = (const float*)d_in[13];

  // workspace layout (148,897,792 B total):
  //   [0,2M)      w gate logits f32
  //   [2M,66M)    zb  (z bf16)        -- layer2 output h2 aliases here
  //   [66M,130M)  h1 bf16             -- gating scratch g1/g2 aliases here
  //   [130M,142M) Wt: 3x8x512x512 bf16 [l][e][o][i]
  char* ws = (char*)d_ws;
  float* wq = (float*)ws;
  unsigned short* zb = (unsigned short*)(ws + (size_t)(2u << 20));
  unsigned short* h1 = (unsigned short*)(ws + (size_t)(66u << 20));
  unsigned short* Wt = (unsigned short*)(ws + (size_t)(130u << 20));
  float* gscr = (float*)h1;       // gating done before layer1 writes h1
  unsigned short* h2 = zb;        // zb dead after layer1

  gating_kernel<<<dim3(256), dim3(256), 0, stream>>>(
      z, idx, Wg1, bg1, Wg2, bg2, Wg3, bg3, wq, gscr);
  convert_bf16_k<<<dim3(16384), dim3(256), 0, stream>>>(z, zb);
  transpose_w<<<dim3(16, 16, 24), dim3(256), 0, stream>>>(W1, W2, W3, Wt);

  expert_layer<true, true><<<dim3(2048), dim3(256), 0, stream>>>(
      zb, Wt, b1, wq, (void*)h1);
  expert_layer<true, true><<<dim3(2048), dim3(256), 0, stream>>>(
      h1, Wt + (size_t)8 * 262144, b2, wq, (void*)h2);
  expert_layer<false, false><<<dim3(2048), dim3(256), 0, stream>>>(
      h2, Wt + (size_t)16 * 262144, b3, wq, d_out);
}

// Round 2
// 1159.810 us; speedup vs baseline: 1.2123x; 1.2123x over previous
//
#include <hip/hip_runtime.h>

#define B_ROWS 65536

typedef __attribute__((ext_vector_type(8))) __bf16 bf16x8;
typedef __attribute__((ext_vector_type(8))) _Float16 f16x8;
typedef __attribute__((ext_vector_type(4))) float f32x4;
typedef __attribute__((ext_vector_type(8))) unsigned short u16x8;

__device__ __forceinline__ unsigned short f2bf(float f) {
  unsigned int u = __float_as_uint(f);
  u += 0x7fffu + ((u >> 16) & 1u);   // RNE
  return (unsigned short)(u >> 16);
}

__device__ __forceinline__ float elu_f(float v) {
  return v > 0.f ? v : __expf(v) - 1.f;
}

__device__ __forceinline__ void async_ld16(const void* g, void* l) {
  __builtin_amdgcn_global_load_lds(
      (const __attribute__((address_space(1))) void*)g,
      (__attribute__((address_space(3))) void*)l, 16, 0, 0);
}

// ---------------- fused gating MLP (f16 MFMA, f32 acc) + z->bf16 convert ----
// 512 blocks x 128 rows. W tiles staged whole in LDS (padded stride 136 f16).
// Activations stay in LDS; logits w written f32. f16 keeps w error ~0.1% rel.
#define GP 136  // padded LDS row stride in f16 (272 B -> 2-way banks = free)

__global__ __launch_bounds__(256) void gating_mfma(
    const float* __restrict__ z, const int* __restrict__ idx,
    const float* __restrict__ Wg1, const float* __restrict__ bg1,
    const float* __restrict__ Wg2, const float* __restrict__ bg2,
    const float* __restrict__ Wg3, const float* __restrict__ bg3,
    float* __restrict__ wq, unsigned short* __restrict__ zb) {
  __shared__ _Float16 Ab[128 * GP];   // activations [row][k]
  __shared__ _Float16 Wb[128 * GP];   // W^T [n][k]
  __shared__ int idx_l[128];

  const int tid = threadIdx.x;
  const int lane = tid & 63, wave = tid >> 6;
  const int wr = wave >> 1, wc = wave & 1;
  const int lhi = lane >> 4, llo = lane & 15;
  const size_t row0 = (size_t)blockIdx.x * 128;

  if (tid < 128) idx_l[tid] = idx[tid];
  // stage W1^T: Wg1[k][n] -> Wb[n][k] f16
  for (int i = tid; i < 16384; i += 256) {
    const int k = i >> 7, n = i & 127;
    Wb[n * GP + k] = (_Float16)Wg1[i];
  }
  // fold in z -> bf16 convert for this block's 128 rows (warms L2 for gather)
  {
    const float* zr = z + row0 * 512;
    unsigned short* zo = zb + row0 * 512;
    for (int i = tid; i < 8192; i += 256) {
      const size_t off = (size_t)i * 8;
      float4 a = *(const float4*)(zr + off);
      float4 b = *(const float4*)(zr + off + 4);
      u16x8 r;
      r[0] = f2bf(a.x); r[1] = f2bf(a.y); r[2] = f2bf(a.z); r[3] = f2bf(a.w);
      r[4] = f2bf(b.x); r[5] = f2bf(b.y); r[6] = f2bf(b.z); r[7] = f2bf(b.w);
      *(u16x8*)(zo + off) = r;
    }
  }
  __syncthreads();
  // gather + convert x tile: Ab[r][c] = z[row0+r][idx[c]]
  for (int i = tid; i < 16384; i += 256) {
    const int r = i >> 7, c = i & 127;
    Ab[r * GP + c] = (_Float16)z[(row0 + r) * 512 + idx_l[c]];
  }
  __syncthreads();

  const f32x4 vzero = {0.f, 0.f, 0.f, 0.f};

  // ---- layer 1: [128x128] @ [128x128] ----
  f32x4 C[4][4];
#pragma unroll
  for (int i = 0; i < 4; i++)
#pragma unroll
    for (int j = 0; j < 4; j++) C[i][j] = vzero;
#pragma unroll
  for (int ks = 0; ks < 4; ks++) {
    f16x8 av[4], bv[4];
#pragma unroll
    for (int fm = 0; fm < 4; fm++)
      av[fm] = *(const f16x8*)&Ab[(wr * 64 + fm * 16 + llo) * GP + ks * 32 + lhi * 8];
#pragma unroll
    for (int fn = 0; fn < 4; fn++)
      bv[fn] = *(const f16x8*)&Wb[(wc * 64 + fn * 16 + llo) * GP + ks * 32 + lhi * 8];
#pragma unroll
    for (int fm = 0; fm < 4; fm++)
#pragma unroll
      for (int fn = 0; fn < 4; fn++)
        C[fm][fn] = __builtin_amdgcn_mfma_f32_16x16x32_f16(av[fm], bv[fn], C[fm][fn], 0, 0, 0);
  }
  __syncthreads();  // all reads of Ab/Wb done
  // g1 = elu(C + bg1) -> Ab ; stage W2^T -> Wb
#pragma unroll
  for (int fm = 0; fm < 4; fm++)
#pragma unroll
    for (int fn = 0; fn < 4; fn++) {
      const int col = wc * 64 + fn * 16 + llo;
      const float bb = bg1[col];
#pragma unroll
      for (int r = 0; r < 4; r++) {
        const int row = wr * 64 + fm * 16 + lhi * 4 + r;
        Ab[row * GP + col] = (_Float16)elu_f(C[fm][fn][r] + bb);
      }
    }
  for (int i = tid; i < 16384; i += 256) {
    const int k = i >> 7, n = i & 127;
    Wb[n * GP + k] = (_Float16)Wg2[i];
  }
  __syncthreads();

  // ---- layer 2 ----
#pragma unroll
  for (int i = 0; i < 4; i++)
#pragma unroll
    for (int j = 0; j < 4; j++) C[i][j] = vzero;
#pragma unroll
  for (int ks = 0; ks < 4; ks++) {
    f16x8 av[4], bv[4];
#pragma unroll
    for (int fm = 0; fm < 4; fm++)
      av[fm] = *(const f16x8*)&Ab[(wr * 64 + fm * 16 + llo) * GP + ks * 32 + lhi * 8];
#pragma unroll
    for (int fn = 0; fn < 4; fn++)
      bv[fn] = *(const f16x8*)&Wb[(wc * 64 + fn * 16 + llo) * GP + ks * 32 + lhi * 8];
#pragma unroll
    for (int fm = 0; fm < 4; fm++)
#pragma unroll
      for (int fn = 0; fn < 4; fn++)
        C[fm][fn] = __builtin_amdgcn_mfma_f32_16x16x32_f16(av[fm], bv[fn], C[fm][fn], 0, 0, 0);
  }
  __syncthreads();
  // g2 = elu(C + bg2) -> Ab ; stage W3^T (padded to 16 cols) -> Wb
#pragma unroll
  for (int fm = 0; fm < 4; fm++)
#pragma unroll
    for (int fn = 0; fn < 4; fn++) {
      const int col = wc * 64 + fn * 16 + llo;
      const float bb = bg2[col];
#pragma unroll
      for (int r = 0; r < 4; r++) {
        const int row = wr * 64 + fm * 16 + lhi * 4 + r;
        Ab[row * GP + col] = (_Float16)elu_f(C[fm][fn][r] + bb);
      }
    }
  for (int i = tid; i < 2048; i += 256) {
    const int k = i >> 4, n = i & 15;
    Wb[n * GP + k] = (n < 8) ? (_Float16)Wg3[k * 8 + n] : (_Float16)0.f;
  }
  __syncthreads();

  // ---- layer 3: [128x128] @ [128x8] (only wc==0 waves store) ----
  f32x4 C3[4];
#pragma unroll
  for (int i = 0; i < 4; i++) C3[i] = vzero;
#pragma unroll
  for (int ks = 0; ks < 4; ks++) {
    f16x8 av[4];
#pragma unroll
    for (int fm = 0; fm < 4; fm++)
      av[fm] = *(const f16x8*)&Ab[(wr * 64 + fm * 16 + llo) * GP + ks * 32 + lhi * 8];
    const f16x8 bv = *(const f16x8*)&Wb[llo * GP + ks * 32 + lhi * 8];
#pragma unroll
    for (int fm = 0; fm < 4; fm++)
      C3[fm] = __builtin_amdgcn_mfma_f32_16x16x32_f16(av[fm], bv, C3[fm], 0, 0, 0);
  }
  if (wc == 0 && llo < 8) {
    const float bb = bg3[llo];
#pragma unroll
    for (int fm = 0; fm < 4; fm++)
#pragma unroll
      for (int r = 0; r < 4; r++) {
        const size_t row = row0 + wr * 64 + fm * 16 + lhi * 4 + r;
        wq[row * 8 + llo] = C3[fm][r] + bb;
      }
  }
}

// ---------------- W[e][i][o] f32 -> Wt[e][o][i] bf16 (B^T layout) ----------
__global__ __launch_bounds__(256) void transpose_w(
    const float* __restrict__ W1, const float* __restrict__ W2,
    const float* __restrict__ W3, unsigned short* __restrict__ Wt) {
  __shared__ float t[32][33];
  const int le = blockIdx.z;  // layer*8 + e, 0..23
  const float* W = (le < 8) ? W1 : (le < 16) ? W2 : W3;
  const size_t eoff = (size_t)(le & 7) * 262144;
  unsigned short* O = Wt + (size_t)le * 262144;
  const int i0 = blockIdx.y * 32, o0 = blockIdx.x * 32;
  const int tx = threadIdx.x & 31, ty = threadIdx.x >> 5;
#pragma unroll
  for (int s = 0; s < 4; s++)
    t[ty + s * 8][tx] = W[eoff + (size_t)(i0 + ty + s * 8) * 512 + o0 + tx];
  __syncthreads();
#pragma unroll
  for (int s = 0; s < 4; s++)
    O[(size_t)(o0 + ty + s * 8) * 512 + i0 + tx] = f2bf(t[tx][ty + s * 8]);
}

// ---------------- soft-MoE expert layer: out = sum_e w_e*(X@W_e + b_e) -----
// 128x128 tile, BK=64, 4 waves (each 64x64 = 4x4 frags of 16x16x32 bf16 MFMA).
// Staging via global_load_lds(16B) with XOR chunk swizzle; per-expert AGPR
// partial combined into fp32 C with per-row gate weight from LDS.
template <bool ELU, bool OUTBF>
__global__ __launch_bounds__(256, 2) void expert_layer(
    const unsigned short* __restrict__ X,   // 65536 x 512 bf16
    const unsigned short* __restrict__ Wt,  // 8 x 512 x 512 bf16 [e][o][i]
    const float* __restrict__ bias,         // 8 x 512 f32 [e][o]
    const float* __restrict__ wq,           // 65536 x 8 f32
    void* __restrict__ Out) {
  __shared__ short a_tile[128 * 64];   // 16 KB, rows of 8 swizzled 16B chunks
  __shared__ short b_tile[128 * 64];   // 16 KB
  __shared__ float w_lds[8 * 128];     // [e][row]  (transposed for b128 reads)
  __shared__ float bias_lds[8 * 128];  // [e][col]

  const int tid = threadIdx.x;
  const int lane = tid & 63;
  const int wave = tid >> 6;
  const int wr = wave >> 1, wc = wave & 1;
  const int lhi = lane >> 4, llo = lane & 15;

  // XCD-aware swizzle: each XCD owns a contiguous m-range, n fast within it
  const int g = blockIdx.x;
  const int xcd = g & 7;
  const int s = g >> 3;
  const int nb = s & 3;
  const int mb = xcd * 64 + (s >> 2);
  const size_t row0 = (size_t)mb * 128;
  const int col0 = nb * 128;

  for (int i = tid; i < 1024; i += 256) {
    const int e = i >> 7, r = i & 127;
    w_lds[i] = wq[(row0 + r) * 8 + e];
    bias_lds[i] = bias[e * 512 + col0 + r];
  }

  const int srow = tid >> 3;                     // 0..31 staged rows/round
  const int cgo = ((tid & 7) ^ (srow & 7)) << 4; // swizzled global 16B chunk
  const char* Ab = (const char*)X + (row0 + srow) * 1024 + cgo;
  const char* Bb = (const char*)Wt + (size_t)(col0 + srow) * 1024 + cgo;
  char* aL = (char*)a_tile + tid * 16;
  char* bL = (char*)b_tile + tid * 16;

  const f32x4 vzero = {0.f, 0.f, 0.f, 0.f};
  f32x4 C[4][4];
#pragma unroll
  for (int i = 0; i < 4; i++)
#pragma unroll
    for (int j = 0; j < 4; j++) C[i][j] = vzero;

  const int rsw = llo & 7;  // frag-read swizzle key (row & 7)

  for (int e = 0; e < 8; e++) {
    f32x4 acc[4][4];
#pragma unroll
    for (int i = 0; i < 4; i++)
#pragma unroll
      for (int j = 0; j < 4; j++) acc[i][j] = vzero;
    const char* Be = Bb + (size_t)e * 524288;
    for (int kt = 0; kt < 8; kt++) {
      const char* ga = Ab + kt * 128;
      const char* gb = Be + kt * 128;
#pragma unroll
      for (int j = 0; j < 4; j++) {
        async_ld16(ga + j * 32768, aL + j * 4096);
        async_ld16(gb + j * 32768, bL + j * 4096);
      }
      __syncthreads();  // drains vmcnt before barrier
#pragma unroll
      for (int ks = 0; ks < 2; ks++) {
        const int slot = (ks * 4 + lhi) ^ rsw;
        bf16x8 av[4], bv[4];
#pragma unroll
        for (int fm = 0; fm < 4; fm++)
          av[fm] = *(const bf16x8*)((const char*)a_tile +
                                    (wr * 64 + fm * 16 + llo) * 128 + slot * 16);
#pragma unroll
        for (int fn = 0; fn < 4; fn++)
          bv[fn] = *(const bf16x8*)((const char*)b_tile +
                                    (wc * 64 + fn * 16 + llo) * 128 + slot * 16);
#pragma unroll
        for (int fm = 0; fm < 4; fm++)
#pragma unroll
          for (int fn = 0; fn < 4; fn++)
            acc[fm][fn] = __builtin_amdgcn_mfma_f32_16x16x32_bf16(
                av[fm], bv[fn], acc[fm][fn], 0, 0, 0);
      }
      __syncthreads();
    }
    // fp32 combine: C += w[row,e] * P_e   (rows = lhi*4 + r -> one b128 read)
#pragma unroll
    for (int fm = 0; fm < 4; fm++) {
      const f32x4 wv =
          *(const f32x4*)(w_lds + e * 128 + wr * 64 + fm * 16 + lhi * 4);
#pragma unroll
      for (int fn = 0; fn < 4; fn++)
#pragma unroll
        for (int r = 0; r < 4; r++) C[fm][fn][r] += wv[r] * acc[fm][fn][r];
    }
  }

  // bias: C += sum_e w[row,e] * b[e,col]  (once per block)
#pragma unroll
  for (int e = 0; e < 8; e++) {
    f32x4 wv[4];
#pragma unroll
    for (int fm = 0; fm < 4; fm++)
      wv[fm] = *(const f32x4*)(w_lds + e * 128 + wr * 64 + fm * 16 + lhi * 4);
#pragma unroll
    for (int fn = 0; fn < 4; fn++) {
      const float bb = bias_lds[e * 128 + wc * 64 + fn * 16 + llo];
#pragma unroll
      for (int fm = 0; fm < 4; fm++)
#pragma unroll
        for (int r = 0; r < 4; r++) C[fm][fn][r] += wv[fm][r] * bb;
    }
  }

  // epilogue: ELU + store (bf16 h or f32 final)
#pragma unroll
  for (int fm = 0; fm < 4; fm++)
#pragma unroll
    for (int fn = 0; fn < 4; fn++)
#pragma unroll
      for (int r = 0; r < 4; r++) {
        float v = C[fm][fn][r];
        if (ELU) v = elu_f(v);
        const size_t orow = row0 + wr * 64 + fm * 16 + lhi * 4 + r;
        const int ocol = col0 + wc * 64 + fn * 16 + llo;
        if (OUTBF)
          ((unsigned short*)Out)[orow * 512 + ocol] = f2bf(v);
        else
          ((float*)Out)[orow * 512 + ocol] = v;
      }
}

extern "C" void kernel_launch(void* const* d_in, const int* in_sizes, int n_in,
                              void* d_out, int out_size, void* d_ws,
                              size_t ws_size, hipStream_t stream) {
  (void)in_sizes; (void)n_in; (void)out_size; (void)ws_size;
  const float* z   = (const float*)d_in[0];
  const int*   idx = (const int*)d_in[1];
  const float* Wg1 = (const float*)d_in[2];
  const float* bg1 = (const float*)d_in[3];
  const float* Wg2 = (const float*)d_in[4];
  const float* bg2 = (const float*)d_in[5];
  const float* Wg3 = (const float*)d_in[6];
  const float* bg3 = (const float*)d_in[7];
  const float* W1  = (const float*)d_in[8];
  const float* b1  = (const float*)d_in[9];
  const float* W2  = (const float*)d_in[10];
  const float* b2  = (const float*)d_in[11];
  const float* W3  = (const float*)d_in[12];
  const float* b3  = (const float*)d_in[13];

  // workspace layout:
  //   [0,2M)      w gate logits f32
  //   [2M,66M)    zb  (z bf16)        -- layer2 output h2 aliases here
  //   [66M,130M)  h1 bf16
  //   [130M,142M) Wt: 3x8x512x512 bf16 [l][e][o][i]
  char* ws = (char*)d_ws;
  float* wq = (float*)ws;
  unsigned short* zb = (unsigned short*)(ws + (size_t)(2u << 20));
  unsigned short* h1 = (unsigned short*)(ws + (size_t)(66u << 20));
  unsigned short* Wt = (unsigned short*)(ws + (size_t)(130u << 20));
  unsigned short* h2 = zb;        // zb dead after layer1

  gating_mfma<<<dim3(512), dim3(256), 0, stream>>>(
      z, idx, Wg1, bg1, Wg2, bg2, Wg3, bg3, wq, zb);
  transpose_w<<<dim3(16, 16, 24), dim3(256), 0, stream>>>(W1, W2, W3, Wt);

  expert_layer<true, true><<<dim3(2048), dim3(256), 0, stream>>>(
      zb, Wt, b1, wq, (void*)h1);
  expert_layer<true, true><<<dim3(2048), dim3(256), 0, stream>>>(
      h1, Wt + (size_t)8 * 262144, b2, wq, (void*)h2);
  expert_layer<false, false><<<dim3(2048), dim3(256), 0, stream>>>(
      h2, Wt + (size_t)16 * 262144, b3, wq, d_out);
}